// Round 4
// baseline (244.151 us; speedup 1.0000x reference)
//
#include <hip/hip_runtime.h>

// (B,C,L,H,W) = (4,64,16,32,32), K=1024, D=C=64
constexpr int Cc   = 64;
constexpr int Kc   = 1024;
constexpr int Dc   = 64;
constexpr int LHWc = 16 * 32 * 32;        // 16384
constexpr int Nc   = 4 * LHWc;            // 65536 vectors
constexpr int QSIZE    = 4 * Cc * LHWc;   // 4194304
constexpr int OFF_LOSS = QSIZE;           // 4194304
constexpr int OFF_IDX  = QSIZE + 1;       // 4194305

constexpr int WAVES  = 4;                 // waves per block (256 threads)
constexpr int KPW    = Kc / WAVES;        // 256 codes per wave

typedef __attribute__((ext_vector_type(16))) float f16v;

__global__ void vq_zero(float* __restrict__ out) {
    out[OFF_LOSS] = 0.0f;
}

// grid = 1024 blocks = exactly 4 blocks/CU; pin occupancy to 4 waves/SIMD so
// the register allocator gets a 128-VGPR budget -> x[64] stays in arch VGPRs
// (round 3's 52-VGPR allocation spilled x to AGPRs: 2 VALU instr per MAC).
__global__ __launch_bounds__(WAVES * 64)
__attribute__((amdgpu_waves_per_eu(4, 4)))
void vq_main(
    const float* __restrict__ in, const float* __restrict__ codebook,
    float* __restrict__ out)
{
    __shared__ float c2s[Kc];                    // ||c_k||^2
    __shared__ unsigned long long red[WAVES * 64];

    const int tid  = threadIdx.x;
    const int lane = tid & 63;
    const int wave = __builtin_amdgcn_readfirstlane(tid >> 6);
    const int k0   = wave * KPW;                 // this wave's code range

    // c2 fill: 256 threads x 4 codes, exact fma chain (same numerics as r2/r3)
#pragma unroll
    for (int j = 0; j < 4; ++j) {
        const int k = tid * 4 + j;
        const float* c = codebook + (size_t)k * Dc;
        float s = 0.f;
#pragma unroll
        for (int d = 0; d < Dc; ++d) s = __builtin_fmaf(c[d], c[d], s);
        c2s[k] = s;
    }
    __syncthreads();

    const int n = blockIdx.x * 64 + lane;        // vector id
    const int b = n >> 14;                       // LHW = 2^14
    const int p = n & (LHWc - 1);

    const float* xin = in + (size_t)b * (Cc * LHWc) + p;

    float x[Dc];
#pragma unroll
    for (int d = 0; d < Dc; ++d) x[d] = xin[(size_t)d * LHWc];

    float x2 = 0.f;
#pragma unroll
    for (int d = 0; d < Dc; ++d) x2 = __builtin_fmaf(x[d], x[d], x2);

    float bestd = __builtin_inff();
    int   bestk = 0;
    const float* ckp = codebook + (size_t)k0 * Dc;

#pragma unroll 1
    for (int kk = 0; kk < KPW; ++kk) {
        f16v c0, c1, c2v, c3;
        // Broadcast codebook row through the scalar pipe: 4 back-to-back
        // s_load_dwordx16 (one round-trip), single wait.
        asm volatile(
            "s_load_dwordx16 %0, %4, 0x0\n\t"
            "s_load_dwordx16 %1, %4, 0x40\n\t"
            "s_load_dwordx16 %2, %4, 0x80\n\t"
            "s_load_dwordx16 %3, %4, 0xc0\n\t"
            "s_waitcnt lgkmcnt(0)"
            : "=s"(c0), "=s"(c1), "=s"(c2v), "=s"(c3)
            : "s"(ckp));

        // exact sequential fma chain over d = 0..63 (bit-identical to r2/r3)
        float acc = 0.f;
#pragma unroll
        for (int j = 0; j < 16; ++j) acc = __builtin_fmaf(x[j],      c0[j], acc);
#pragma unroll
        for (int j = 0; j < 16; ++j) acc = __builtin_fmaf(x[16 + j], c1[j], acc);
#pragma unroll
        for (int j = 0; j < 16; ++j) acc = __builtin_fmaf(x[32 + j], c2v[j], acc);
#pragma unroll
        for (int j = 0; j < 16; ++j) acc = __builtin_fmaf(x[48 + j], c3[j], acc);

        // reference rounding: d2 = fl(fl(x2 - fl(2*dot)) + c2)
        float t  = __builtin_fmaf(-2.0f, acc, x2);
        float d2 = t + c2s[k0 + kk];

        // strict < with ascending k == first-index tie-break (3 VALU)
        if (d2 < bestd) { bestd = d2; bestk = kk; }

        ckp += Dc;                               // scalar pointer bump
    }

    // pack for cross-wave reduce; d2 > 0 so float bits order as uint,
    // k in low bits -> u64 min keeps lowest k on ties
    unsigned long long best =
        ((unsigned long long)__float_as_uint(bestd) << 32) |
        (unsigned)(k0 + bestk);

    red[wave * 64 + lane] = best;
    __syncthreads();

    if (wave == 0) {
        unsigned long long bb = red[lane];
#pragma unroll
        for (int w = 1; w < WAVES; ++w) {
            unsigned long long o = red[w * 64 + lane];
            bb = o < bb ? o : bb;                // wave order == k order
        }
        const int k = (int)(bb & 0xffffffffu);

        out[OFF_IDX + n] = (float)k;

        const float* ck = codebook + (size_t)k * Dc;
        float* qout = out + (size_t)b * (Cc * LHWc) + p;
        float lsum = 0.f;
#pragma unroll
        for (int c = 0; c < Dc; ++c) {
            float q = ck[c];
            qout[(size_t)c * LHWc] = q;          // coalesced across lanes per c
            float e = q - x[c];
            lsum = __builtin_fmaf(e, e, lsum);
        }
#pragma unroll
        for (int off = 32; off > 0; off >>= 1)
            lsum += __shfl_down(lsum, off, 64);
        if (lane == 0)
            atomicAdd(&out[OFF_LOSS], lsum * (1.25f / (float)QSIZE));
    }
}

extern "C" void kernel_launch(void* const* d_in, const int* in_sizes, int n_in,
                              void* d_out, int out_size, void* d_ws, size_t ws_size,
                              hipStream_t stream) {
    const float* in = (const float*)d_in[0];   // [4,64,16,32,32] f32
    const float* cb = (const float*)d_in[1];   // [1024,64] f32
    float* out = (float*)d_out;
    (void)d_ws; (void)ws_size;

    vq_zero<<<dim3(1), dim3(1), 0, stream>>>(out);
    vq_main<<<dim3(Nc / 64), dim3(WAVES * 64), 0, stream>>>(in, cb, out);
}